// Round 1
// baseline (17709.729 us; speedup 1.0000x reference)
//
#include <hip/hip_runtime.h>
#include <cstdint>

#define EPSLN 1e-5f

// ---------------------------------------------------------------------------
// K0: degree count (dst occurrences; +1 self-loop added in k_dinv)
// ---------------------------------------------------------------------------
__global__ void k_deg(const int* __restrict__ dst, int* __restrict__ deg, int E) {
    int e = blockIdx.x * blockDim.x + threadIdx.x;
    if (e >= E) return;
    atomicAdd(&deg[dst[e]], 1);
}

__global__ void k_dinv(const int* __restrict__ deg, float* __restrict__ dinv, int N) {
    int v = blockIdx.x * blockDim.x + threadIdx.x;
    if (v >= N) return;
    dinv[v] = rsqrtf((float)(deg[v] + 1));  // +1: self-loop
}

// ---------------------------------------------------------------------------
// Edge scatter: agg[dst] += dinv[src]*dinv[dst] * x[src]   (F floats per edge)
// Self-loop handled analytically in the node kernels.
// ---------------------------------------------------------------------------
template <int F>
__global__ __launch_bounds__(256) void k_edge(const int* __restrict__ src,
                                              const int* __restrict__ dst,
                                              const float* __restrict__ dinv,
                                              const float* __restrict__ x,
                                              float* __restrict__ agg, int E) {
    int e = blockIdx.x * blockDim.x + threadIdx.x;
    if (e >= E) return;
    int s = src[e];
    int d = dst[e];
    float w = dinv[s] * dinv[d];
    float vals[F];
    if constexpr (F == 6) {
        const float2* x2 = (const float2*)x;  // rows are 24B = 3 x float2, 8B-aligned
        float2 a = x2[(size_t)s * 3 + 0];
        float2 b = x2[(size_t)s * 3 + 1];
        float2 c = x2[(size_t)s * 3 + 2];
        vals[0] = a.x; vals[1] = a.y; vals[2] = b.x;
        vals[3] = b.y; vals[4] = c.x; vals[5] = c.y;
    } else {
#pragma unroll
        for (int f = 0; f < F; ++f) vals[f] = x[(size_t)s * F + f];
    }
#pragma unroll
    for (int f = 0; f < F; ++f)
        unsafeAtomicAdd(&agg[(size_t)d * F + f], w * vals[f]);
}

// ---------------------------------------------------------------------------
// Conv-1 node kernel: x0 = (agg3 + dinv^2 * node) @ W1 + b1     [N,3]->[N,6]
// ---------------------------------------------------------------------------
__global__ void k_node_first(const float* __restrict__ agg,   // [N,3]
                             const float* __restrict__ node,  // [N,3]
                             const float* __restrict__ dinv,
                             const float* __restrict__ W1,    // [3,6]
                             const float* __restrict__ b1,    // [6]
                             float* __restrict__ xout,        // [N,6]
                             int N) {
    int v = blockIdx.x * blockDim.x + threadIdx.x;
    if (v >= N) return;
    float di = dinv[v];
    float w2 = di * di;
    float t[3];
#pragma unroll
    for (int k = 0; k < 3; ++k)
        t[k] = agg[(size_t)v * 3 + k] + w2 * node[(size_t)v * 3 + k];
#pragma unroll
    for (int j = 0; j < 6; ++j) {
        float acc = b1[j];
#pragma unroll
        for (int k = 0; k < 3; ++k) acc += t[k] * W1[k * 6 + j];
        xout[(size_t)v * 6 + j] = acc;
    }
}

// ---------------------------------------------------------------------------
// Layer node kernel: y = (agg6 + dinv^2*x) @ W + b ; LN ; +res ; relu
// If `final`, additionally emits  relu_out @ Wfc + bfc  into outfc and skips xout.
// ---------------------------------------------------------------------------
__global__ void k_node_layer(const float* __restrict__ agg,   // [N,6]
                             const float* __restrict__ xin,   // [N,6]
                             const float* __restrict__ dinv,
                             const float* __restrict__ W,     // [6,6]
                             const float* __restrict__ b,     // [6]
                             const float* __restrict__ gamma, // [6]
                             const float* __restrict__ beta,  // [6]
                             float* __restrict__ xout,        // [N,6]
                             const float* __restrict__ Wfc,   // [6,3]
                             const float* __restrict__ bfc,   // [3]
                             float* __restrict__ outfc,       // [N,3]
                             int N, int is_final) {
    int v = blockIdx.x * blockDim.x + threadIdx.x;
    if (v >= N) return;
    float di = dinv[v];
    float w2 = di * di;
    float xi[6], t[6], y[6];
#pragma unroll
    for (int k = 0; k < 6; ++k) {
        xi[k] = xin[(size_t)v * 6 + k];
        t[k]  = agg[(size_t)v * 6 + k] + w2 * xi[k];
    }
#pragma unroll
    for (int j = 0; j < 6; ++j) {
        float acc = b[j];
#pragma unroll
        for (int k = 0; k < 6; ++k) acc += t[k] * W[k * 6 + j];
        y[j] = acc;
    }
    // LayerNorm over 6 features
    float mu = 0.f;
#pragma unroll
    for (int j = 0; j < 6; ++j) mu += y[j];
    mu *= (1.f / 6.f);
    float var = 0.f;
#pragma unroll
    for (int j = 0; j < 6; ++j) { float dl = y[j] - mu; var += dl * dl; }
    var *= (1.f / 6.f);
    float rs = rsqrtf(var + EPSLN);
    float r[6];
#pragma unroll
    for (int j = 0; j < 6; ++j) {
        float z = (y[j] - mu) * rs * gamma[j] + beta[j] + xi[j];
        r[j] = z > 0.f ? z : 0.f;
    }
    if (!is_final) {
#pragma unroll
        for (int j = 0; j < 6; ++j) xout[(size_t)v * 6 + j] = r[j];
    } else {
#pragma unroll
        for (int j = 0; j < 3; ++j) {
            float acc = bfc[j];
#pragma unroll
            for (int k = 0; k < 6; ++k) acc += r[k] * Wfc[k * 3 + j];
            outfc[(size_t)v * 3 + j] = acc;
        }
    }
}

// ---------------------------------------------------------------------------
extern "C" void kernel_launch(void* const* d_in, const int* in_sizes, int n_in,
                              void* d_out, int out_size, void* d_ws, size_t ws_size,
                              hipStream_t stream) {
    const float* node  = (const float*)d_in[0];
    const int*   edges = (const int*)d_in[1];   // harness materializes ints as int32
    const float* W1    = (const float*)d_in[2];
    const float* b1    = (const float*)d_in[3];
    const float* Wl    = (const float*)d_in[4];
    const float* bl    = (const float*)d_in[5];
    const float* gamma = (const float*)d_in[6];
    const float* beta  = (const float*)d_in[7];
    const float* Wfc   = (const float*)d_in[8];
    const float* bfc   = (const float*)d_in[9];
    float* out = (float*)d_out;

    const int N     = in_sizes[0] / 3;
    const int E     = in_sizes[1] / 2;
    const int STEPS = in_sizes[4] / 36;
    const int* src = edges;        // edges[0, :]
    const int* dst = edges + E;    // edges[1, :]

    char* ws = (char*)d_ws;
    size_t off = 0;
    auto alloc = [&](size_t bytes) -> void* {
        void* p = ws + off;
        off += (bytes + 255) & ~(size_t)255;
        return p;
    };
    int*   deg  = (int*)alloc((size_t)N * sizeof(int));
    float* dinv = (float*)alloc((size_t)N * sizeof(float));
    float* agg  = (float*)alloc((size_t)N * 6 * sizeof(float));
    float* xa   = (float*)alloc((size_t)N * 6 * sizeof(float));
    float* xb   = (float*)alloc((size_t)N * 6 * sizeof(float));
    (void)ws_size;

    const int T = 256;
    const int gE = (E + T - 1) / T;
    const int gN = (N + T - 1) / T;

    // Degree + dinv (ws is poisoned each call -> recompute)
    hipMemsetAsync(deg, 0, (size_t)N * sizeof(int), stream);
    k_deg<<<gE, T, 0, stream>>>(dst, deg, E);
    k_dinv<<<gN, T, 0, stream>>>(deg, dinv, N);

    // Conv 1: aggregate raw node features (F=3), then (Ax)@W1 + b1
    hipMemsetAsync(agg, 0, (size_t)N * 3 * sizeof(float), stream);
    k_edge<3><<<gE, T, 0, stream>>>(src, dst, dinv, node, agg, E);
    k_node_first<<<gN, T, 0, stream>>>(agg, node, dinv, W1, b1, xa, N);

    float* xcur = xa;
    float* xnxt = xb;
    for (int i = 0; i < STEPS; ++i) {
        hipMemsetAsync(agg, 0, (size_t)N * 6 * sizeof(float), stream);
        k_edge<6><<<gE, T, 0, stream>>>(src, dst, dinv, xcur, agg, E);
        int fin = (i == STEPS - 1) ? 1 : 0;
        k_node_layer<<<gN, T, 0, stream>>>(agg, xcur, dinv,
                                           Wl + (size_t)i * 36, bl + (size_t)i * 6,
                                           gamma + (size_t)i * 6, beta + (size_t)i * 6,
                                           xnxt, Wfc, bfc, out, N, fin);
        float* tmp = xcur; xcur = xnxt; xnxt = tmp;
    }
}

// Round 2
// 2412.768 us; speedup vs baseline: 7.3400x; 7.3400x over previous
//
#include <hip/hip_runtime.h>
#include <cstdint>

#define EPSLN 1e-5f
#define SCAN_B 1024

// ---------------------------------------------------------------------------
// Degree count over dst (self-loop added analytically later as deg+1)
// ---------------------------------------------------------------------------
__global__ __launch_bounds__(256) void k_deg(const int* __restrict__ dst,
                                             int* __restrict__ deg, int E) {
    int e = blockIdx.x * blockDim.x + threadIdx.x;
    if (e < E) atomicAdd(&deg[__builtin_nontemporal_load(dst + e)], 1);
}

// ---------------------------------------------------------------------------
// Two-level exclusive scan of deg -> ptr
// ---------------------------------------------------------------------------
__global__ __launch_bounds__(SCAN_B) void k_scan1(const int* __restrict__ deg,
                                                  int* __restrict__ ptr,
                                                  int* __restrict__ bsum, int N) {
    __shared__ int sm[SCAN_B];
    int i = blockIdx.x * SCAN_B + threadIdx.x;
    int v = (i < N) ? deg[i] : 0;
    sm[threadIdx.x] = v;
    __syncthreads();
    for (int off = 1; off < SCAN_B; off <<= 1) {
        int t = (threadIdx.x >= off) ? sm[threadIdx.x - off] : 0;
        __syncthreads();
        sm[threadIdx.x] += t;
        __syncthreads();
    }
    if (i < N) ptr[i] = sm[threadIdx.x] - v;  // exclusive within block
    if (threadIdx.x == SCAN_B - 1) bsum[blockIdx.x] = sm[threadIdx.x];
}

__global__ __launch_bounds__(SCAN_B) void k_scan2(int* __restrict__ bsum, int nb) {
    __shared__ int sm[SCAN_B];
    int v = (threadIdx.x < nb) ? bsum[threadIdx.x] : 0;
    sm[threadIdx.x] = v;
    __syncthreads();
    for (int off = 1; off < SCAN_B; off <<= 1) {
        int t = (threadIdx.x >= off) ? sm[threadIdx.x - off] : 0;
        __syncthreads();
        sm[threadIdx.x] += t;
        __syncthreads();
    }
    if (threadIdx.x < nb) bsum[threadIdx.x] = sm[threadIdx.x] - v;  // exclusive
}

// Finalize: global ptr, cursor copy, dinv, and pre-scaled first-layer features
__global__ __launch_bounds__(256) void k_fin(int* __restrict__ ptr,
                                             const int* __restrict__ bsum,
                                             const int* __restrict__ deg,
                                             float* __restrict__ dinv,
                                             int* __restrict__ cursor,
                                             const float* __restrict__ node,
                                             float* __restrict__ xs3,
                                             int N, int E) {
    int i = blockIdx.x * blockDim.x + threadIdx.x;
    if (i < N) {
        int p = ptr[i] + bsum[i / SCAN_B];
        ptr[i] = p;
        cursor[i] = p;
        float di = rsqrtf((float)(deg[i] + 1));  // +1: self-loop
        dinv[i] = di;
        xs3[(size_t)i * 3 + 0] = di * node[(size_t)i * 3 + 0];
        xs3[(size_t)i * 3 + 1] = di * node[(size_t)i * 3 + 1];
        xs3[(size_t)i * 3 + 2] = di * node[(size_t)i * 3 + 2];
    } else if (i == N) {
        ptr[N] = E;
    }
}

// ---------------------------------------------------------------------------
// Counting-sort scatter: place src index into the dst's CSR segment
// ---------------------------------------------------------------------------
__global__ __launch_bounds__(256) void k_build(const int* __restrict__ src,
                                               const int* __restrict__ dst,
                                               int* __restrict__ cursor,
                                               int* __restrict__ csr, int E) {
    int e = blockIdx.x * blockDim.x + threadIdx.x;
    if (e >= E) return;
    int d = __builtin_nontemporal_load(dst + e);
    int s = __builtin_nontemporal_load(src + e);
    int pos = atomicAdd(&cursor[d], 1);
    csr[pos] = s;
}

// ---------------------------------------------------------------------------
// Fused conv: wave-per-node gather reduce + per-node dense/LN/relu/FC
// MODE 0: first conv (F=3 in) -> x0, xs0
// MODE 1: mid layer  (F=6 in) -> LN+res+relu -> x, xs
// MODE 2: final layer         -> LN+res+relu -> @Wfc+bfc -> out
// ---------------------------------------------------------------------------
template <int MODE>
__global__ __launch_bounds__(256) void k_conv(const int* __restrict__ ptr,
                                              const int* __restrict__ csr,
                                              const float* __restrict__ dinv,
                                              const float* __restrict__ xs,   // scaled [N,F]
                                              const float* __restrict__ xin,  // residual [N,6]
                                              const float* __restrict__ W,
                                              const float* __restrict__ b,
                                              const float* __restrict__ gamma,
                                              const float* __restrict__ beta,
                                              const float* __restrict__ Wfc,
                                              const float* __restrict__ bfc,
                                              float* __restrict__ xout,
                                              float* __restrict__ xsout,
                                              float* __restrict__ outfc,
                                              int N) {
    constexpr int F = (MODE == 0) ? 3 : 6;
    int wave = threadIdx.x >> 6;
    int lane = threadIdx.x & 63;
    int v = blockIdx.x * 4 + wave;
    if (v >= N) return;
    int beg = ptr[v], end = ptr[v + 1];

    float a0 = 0.f, a1 = 0.f, a2 = 0.f, a3 = 0.f, a4 = 0.f, a5 = 0.f;
    if constexpr (F == 3) {
        for (int i = beg + lane; i < end; i += 64) {
            int s = __builtin_nontemporal_load(csr + i);
            const float* xr = xs + (size_t)s * 3;
            a0 += xr[0]; a1 += xr[1]; a2 += xr[2];
        }
        if (lane == 0) {  // self-loop
            const float* xr = xs + (size_t)v * 3;
            a0 += xr[0]; a1 += xr[1]; a2 += xr[2];
        }
    } else {
        const float2* xs2 = (const float2*)xs;
        for (int i = beg + lane; i < end; i += 64) {
            int s = __builtin_nontemporal_load(csr + i);
            float2 p = xs2[(size_t)s * 3 + 0];
            float2 q = xs2[(size_t)s * 3 + 1];
            float2 r = xs2[(size_t)s * 3 + 2];
            a0 += p.x; a1 += p.y; a2 += q.x; a3 += q.y; a4 += r.x; a5 += r.y;
        }
        if (lane == 0) {  // self-loop
            float2 p = xs2[(size_t)v * 3 + 0];
            float2 q = xs2[(size_t)v * 3 + 1];
            float2 r = xs2[(size_t)v * 3 + 2];
            a0 += p.x; a1 += p.y; a2 += q.x; a3 += q.y; a4 += r.x; a5 += r.y;
        }
    }
#pragma unroll
    for (int off = 32; off >= 1; off >>= 1) {
        a0 += __shfl_down(a0, off);
        a1 += __shfl_down(a1, off);
        a2 += __shfl_down(a2, off);
        if constexpr (F == 6) {
            a3 += __shfl_down(a3, off);
            a4 += __shfl_down(a4, off);
            a5 += __shfl_down(a5, off);
        }
    }
    if (lane != 0) return;

    float di = dinv[v];
    float t[F];
    t[0] = di * a0; t[1] = di * a1; t[2] = di * a2;
    if constexpr (F == 6) { t[3] = di * a3; t[4] = di * a4; t[5] = di * a5; }

    float y[6];
#pragma unroll
    for (int j = 0; j < 6; ++j) {
        float acc = b[j];
#pragma unroll
        for (int k = 0; k < F; ++k) acc += t[k] * W[k * 6 + j];
        y[j] = acc;
    }

    if constexpr (MODE == 0) {
        float2* xo = (float2*)(xout + (size_t)v * 6);
        float2* xso = (float2*)(xsout + (size_t)v * 6);
        xo[0] = make_float2(y[0], y[1]);
        xo[1] = make_float2(y[2], y[3]);
        xo[2] = make_float2(y[4], y[5]);
        xso[0] = make_float2(di * y[0], di * y[1]);
        xso[1] = make_float2(di * y[2], di * y[3]);
        xso[2] = make_float2(di * y[4], di * y[5]);
    } else {
        // LayerNorm over 6
        float mu = 0.f;
#pragma unroll
        for (int j = 0; j < 6; ++j) mu += y[j];
        mu *= (1.f / 6.f);
        float var = 0.f;
#pragma unroll
        for (int j = 0; j < 6; ++j) { float dl = y[j] - mu; var += dl * dl; }
        var *= (1.f / 6.f);
        float rs = rsqrtf(var + EPSLN);
        const float* xr = xin + (size_t)v * 6;
        float r[6];
#pragma unroll
        for (int j = 0; j < 6; ++j) {
            float z = (y[j] - mu) * rs * gamma[j] + beta[j] + xr[j];
            r[j] = z > 0.f ? z : 0.f;
        }
        if constexpr (MODE == 1) {
            float2* xo = (float2*)(xout + (size_t)v * 6);
            float2* xso = (float2*)(xsout + (size_t)v * 6);
            xo[0] = make_float2(r[0], r[1]);
            xo[1] = make_float2(r[2], r[3]);
            xo[2] = make_float2(r[4], r[5]);
            xso[0] = make_float2(di * r[0], di * r[1]);
            xso[1] = make_float2(di * r[2], di * r[3]);
            xso[2] = make_float2(di * r[4], di * r[5]);
        } else {
#pragma unroll
            for (int j = 0; j < 3; ++j) {
                float acc = bfc[j];
#pragma unroll
                for (int k = 0; k < 6; ++k) acc += r[k] * Wfc[k * 3 + j];
                outfc[(size_t)v * 3 + j] = acc;
            }
        }
    }
}

// ---------------------------------------------------------------------------
extern "C" void kernel_launch(void* const* d_in, const int* in_sizes, int n_in,
                              void* d_out, int out_size, void* d_ws, size_t ws_size,
                              hipStream_t stream) {
    const float* node  = (const float*)d_in[0];
    const int*   edges = (const int*)d_in[1];
    const float* W1    = (const float*)d_in[2];
    const float* b1    = (const float*)d_in[3];
    const float* Wl    = (const float*)d_in[4];
    const float* bl    = (const float*)d_in[5];
    const float* gamma = (const float*)d_in[6];
    const float* beta  = (const float*)d_in[7];
    const float* Wfc   = (const float*)d_in[8];
    const float* bfc   = (const float*)d_in[9];
    float* out = (float*)d_out;

    const int N     = in_sizes[0] / 3;
    const int E     = in_sizes[1] / 2;
    const int STEPS = in_sizes[4] / 36;
    const int* src = edges;
    const int* dst = edges + E;

    char* ws = (char*)d_ws;
    size_t off = 0;
    auto alloc = [&](size_t bytes) -> void* {
        void* p = ws + off;
        off += (bytes + 255) & ~(size_t)255;
        return p;
    };
    const int nb = (N + SCAN_B - 1) / SCAN_B;
    int*   deg    = (int*)alloc((size_t)N * sizeof(int));
    int*   ptr    = (int*)alloc((size_t)(N + 1) * sizeof(int));
    int*   cursor = (int*)alloc((size_t)N * sizeof(int));
    int*   bsum   = (int*)alloc((size_t)nb * sizeof(int));
    float* dinv   = (float*)alloc((size_t)N * sizeof(float));
    int*   csr    = (int*)alloc((size_t)E * sizeof(int));
    float* xs3    = (float*)alloc((size_t)N * 3 * sizeof(float));
    float* xa     = (float*)alloc((size_t)N * 6 * sizeof(float));
    float* xb     = (float*)alloc((size_t)N * 6 * sizeof(float));
    float* xsa    = (float*)alloc((size_t)N * 6 * sizeof(float));
    float* xsb    = (float*)alloc((size_t)N * 6 * sizeof(float));
    (void)ws_size;

    const int T = 256;
    const int gE = (E + T - 1) / T;
    const int gC = (N + 3) / 4;  // wave-per-node conv blocks

    hipMemsetAsync(deg, 0, (size_t)N * sizeof(int), stream);
    k_deg<<<gE, T, 0, stream>>>(dst, deg, E);
    k_scan1<<<nb, SCAN_B, 0, stream>>>(deg, ptr, bsum, N);
    k_scan2<<<1, SCAN_B, 0, stream>>>(bsum, nb);
    k_fin<<<(N + 1 + T - 1) / T, T, 0, stream>>>(ptr, bsum, deg, dinv, cursor, node, xs3, N, E);
    k_build<<<gE, T, 0, stream>>>(src, dst, cursor, csr, E);

    // Conv 1 (F=3): x0 = (A_hat @ node) @ W1 + b1
    k_conv<0><<<gC, T, 0, stream>>>(ptr, csr, dinv, xs3, nullptr, W1, b1,
                                    nullptr, nullptr, nullptr, nullptr,
                                    xa, xsa, nullptr, N);

    float* xcur = xa;  float* xscur = xsa;
    float* xnxt = xb;  float* xsnxt = xsb;
    for (int i = 0; i < STEPS; ++i) {
        const float* W  = Wl + (size_t)i * 36;
        const float* bb = bl + (size_t)i * 6;
        const float* g  = gamma + (size_t)i * 6;
        const float* be = beta + (size_t)i * 6;
        if (i == STEPS - 1) {
            k_conv<2><<<gC, T, 0, stream>>>(ptr, csr, dinv, xscur, xcur, W, bb,
                                            g, be, Wfc, bfc,
                                            nullptr, nullptr, out, N);
        } else {
            k_conv<1><<<gC, T, 0, stream>>>(ptr, csr, dinv, xscur, xcur, W, bb,
                                            g, be, nullptr, nullptr,
                                            xnxt, xsnxt, nullptr, N);
        }
        float* tmp;
        tmp = xcur; xcur = xnxt; xnxt = tmp;
        tmp = xscur; xscur = xsnxt; xsnxt = tmp;
    }
}

// Round 3
// 1259.754 us; speedup vs baseline: 14.0581x; 1.9153x over previous
//
#include <hip/hip_runtime.h>
#include <cstdint>

#define EPSLN 1e-5f
#define NPB 128          // nodes per bucket (power of 2)
#define NPB_SHIFT 7
#define MAXB 2048        // max buckets (supports N <= 262144)
#define TILE 16384       // edges per sort tile
#define FCAP 12288       // k_fine LDS capacity; bucket size ~Poisson(8192), +45 sigma margin

// ---------------------------------------------------------------------------
// Pass 1: per-bucket histogram of dst
// ---------------------------------------------------------------------------
__global__ __launch_bounds__(256) void k_hist(const int* __restrict__ dst,
                                              int* __restrict__ bcount, int E, int B) {
    __shared__ int hist[MAXB];
    for (int b = threadIdx.x; b < B; b += 256) hist[b] = 0;
    __syncthreads();
    int beg = blockIdx.x * TILE;
    int end = min(beg + TILE, E);
    for (int i = beg + threadIdx.x; i < end; i += 256)
        atomicAdd(&hist[__builtin_nontemporal_load(dst + i) >> NPB_SHIFT], 1);
    __syncthreads();
    for (int b = threadIdx.x; b < B; b += 256)
        if (hist[b]) atomicAdd(&bcount[b], hist[b]);
}

// ---------------------------------------------------------------------------
// Pass 2: scan bucket counts -> boff / bcur; also seed ptr[N]=E
// ---------------------------------------------------------------------------
__global__ __launch_bounds__(1024) void k_bscan(const int* __restrict__ bcount,
                                                int* __restrict__ boff,
                                                int* __restrict__ bcur,
                                                int* __restrict__ ptr,
                                                int B, int N, int E) {
    __shared__ int sm[MAXB];
    int i0 = threadIdx.x, i1 = threadIdx.x + 1024;
    int v0 = (i0 < B) ? bcount[i0] : 0;
    int v1 = (i1 < B) ? bcount[i1] : 0;
    sm[i0] = v0; sm[i1] = v1;
    __syncthreads();
    for (int off = 1; off < MAXB; off <<= 1) {
        int t0 = (i0 >= off) ? sm[i0 - off] : 0;
        int t1 = (i1 >= off) ? sm[i1 - off] : 0;
        __syncthreads();
        sm[i0] += t0; sm[i1] += t1;
        __syncthreads();
    }
    if (i0 < B) { int e = sm[i0] - v0; boff[i0] = e; bcur[i0] = e; }
    if (i1 < B) { int e = sm[i1] - v1; boff[i1] = e; bcur[i1] = e; }
    if (threadIdx.x == 0) { boff[B] = E; ptr[N] = E; }
}

// ---------------------------------------------------------------------------
// Pass 3: tiled bucket scatter. Packed word = (dst_local << 24) | src.
// Per-tile range reservation keeps writes in contiguous chunks per bucket.
// ---------------------------------------------------------------------------
__global__ __launch_bounds__(256) void k_scatter(const int* __restrict__ src,
                                                 const int* __restrict__ dst,
                                                 int* __restrict__ bcur,
                                                 int* __restrict__ packed,
                                                 int E, int B) {
    __shared__ int hist[MAXB];
    __shared__ int base[MAXB];
    for (int b = threadIdx.x; b < B; b += 256) hist[b] = 0;
    __syncthreads();
    int beg = blockIdx.x * TILE;
    int end = min(beg + TILE, E);
    for (int i = beg + threadIdx.x; i < end; i += 256)
        atomicAdd(&hist[__builtin_nontemporal_load(dst + i) >> NPB_SHIFT], 1);
    __syncthreads();
    for (int b = threadIdx.x; b < B; b += 256) {
        int c = hist[b];
        base[b] = c ? atomicAdd(&bcur[b], c) : 0;
        hist[b] = 0;
    }
    __syncthreads();
    for (int i = beg + threadIdx.x; i < end; i += 256) {
        int d = dst[i];
        int s = src[i];
        int bkt = d >> NPB_SHIFT;
        int pos = base[bkt] + atomicAdd(&hist[bkt], 1);
        packed[pos] = ((d & (NPB - 1)) << 24) | s;
    }
}

// ---------------------------------------------------------------------------
// Pass 4: per-bucket fine sort (in place, LDS-staged) + fused degree/dinv/
// ptr/xs3 production. One block per bucket; all writes stay in a 32KB window.
// ---------------------------------------------------------------------------
__global__ __launch_bounds__(256) void k_fine(const int* __restrict__ boff,
                                              int* __restrict__ packed,  // in: packed, out: csr (src ids)
                                              int* __restrict__ ptr,
                                              float* __restrict__ dinv,
                                              float* __restrict__ sqd,
                                              const float* __restrict__ node,
                                              float* __restrict__ xs3,   // [N,4] padded
                                              int N) {
    __shared__ int buf[FCAP];
    __shared__ int hist[NPB];
    __shared__ int cur[NPB];
    int b = blockIdx.x;
    int beg = boff[b], end = boff[b + 1];
    int cnt = min(end - beg, FCAP);
    int tid = threadIdx.x;
    if (tid < NPB) hist[tid] = 0;
    __syncthreads();
    for (int i = tid; i < cnt; i += 256) {
        int w = packed[beg + i];
        buf[i] = w;
        atomicAdd(&hist[w >> 24], 1);
    }
    __syncthreads();
    // Hillis-Steele scan over NPB node counts
    int hv = 0;
    if (tid < NPB) { hv = hist[tid]; cur[tid] = hv; }
    __syncthreads();
    for (int off = 1; off < NPB; off <<= 1) {
        int t = 0;
        if (tid < NPB && tid >= off) t = cur[tid - off];
        __syncthreads();
        if (tid < NPB) cur[tid] += t;
        __syncthreads();
    }
    if (tid < NPB) {
        int ex = cur[tid] - hv;  // exclusive
        int v = b * NPB + tid;
        if (v < N) {
            ptr[v] = beg + ex;
            float c = (float)(hv + 1);      // +1: self-loop
            float di = rsqrtf(c);
            dinv[v] = di;
            sqd[v] = sqrtf(c);              // = 1/di, for residual reconstruction
            xs3[(size_t)v * 4 + 0] = di * node[(size_t)v * 3 + 0];
            xs3[(size_t)v * 4 + 1] = di * node[(size_t)v * 3 + 1];
            xs3[(size_t)v * 4 + 2] = di * node[(size_t)v * 3 + 2];
            xs3[(size_t)v * 4 + 3] = 0.f;
        }
        cur[tid] = ex;  // becomes placement cursor
    }
    __syncthreads();
    for (int i = tid; i < cnt; i += 256) {
        int w = buf[i];
        int d = w >> 24;          // dlocal (w >= 0, arithmetic shift safe)
        int s = w & 0xFFFFFF;
        int pos = atomicAdd(&cur[d], 1);
        packed[beg + pos] = s;    // in place: all reads staged in LDS before barrier
    }
}

// ---------------------------------------------------------------------------
// Fused conv: wave-per-node gather reduce + per-node dense/LN/relu/FC
// xs holds dinv-prescaled features. MODE 0: first conv (F=3) -> xsout.
// MODE 1: mid layer -> LN+res+relu -> xsout. MODE 2: final -> @Wfc+bfc -> out.
// ---------------------------------------------------------------------------
template <int MODE>
__global__ __launch_bounds__(256) void k_conv(const int* __restrict__ ptr,
                                              const int* __restrict__ csr,
                                              const float* __restrict__ dinv,
                                              const float* __restrict__ sqd,
                                              const float* __restrict__ xs,   // MODE0: [N,4] else [N,8]
                                              const float* __restrict__ W,
                                              const float* __restrict__ b,
                                              const float* __restrict__ gamma,
                                              const float* __restrict__ beta,
                                              const float* __restrict__ Wfc,
                                              const float* __restrict__ bfc,
                                              float* __restrict__ xsout,      // [N,8]
                                              float* __restrict__ outfc,      // [N,3]
                                              int N) {
    constexpr int F = (MODE == 0) ? 3 : 6;
    int wave = threadIdx.x >> 6;
    int lane = threadIdx.x & 63;
    int v = blockIdx.x * 4 + wave;
    if (v >= N) return;
    int beg = ptr[v], end = ptr[v + 1];

    float a0 = 0.f, a1 = 0.f, a2 = 0.f, a3 = 0.f, a4 = 0.f, a5 = 0.f;
    if constexpr (F == 3) {
        const float4* x4 = (const float4*)xs;
        for (int i = beg + lane; i < end; i += 64) {
            int s = __builtin_nontemporal_load(csr + i);
            float4 p = x4[s];
            a0 += p.x; a1 += p.y; a2 += p.z;
        }
        if (lane == 0) { float4 p = x4[v]; a0 += p.x; a1 += p.y; a2 += p.z; }
    } else {
        for (int i = beg + lane; i < end; i += 64) {
            int s = __builtin_nontemporal_load(csr + i);
            const float* r = xs + (size_t)s * 8;
            float4 p = *(const float4*)r;
            float2 q = *(const float2*)(r + 4);
            a0 += p.x; a1 += p.y; a2 += p.z; a3 += p.w; a4 += q.x; a5 += q.y;
        }
        if (lane == 0) {
            const float* r = xs + (size_t)v * 8;
            float4 p = *(const float4*)r;
            float2 q = *(const float2*)(r + 4);
            a0 += p.x; a1 += p.y; a2 += p.z; a3 += p.w; a4 += q.x; a5 += q.y;
        }
    }
#pragma unroll
    for (int off = 32; off >= 1; off >>= 1) {
        a0 += __shfl_down(a0, off);
        a1 += __shfl_down(a1, off);
        a2 += __shfl_down(a2, off);
        if constexpr (F == 6) {
            a3 += __shfl_down(a3, off);
            a4 += __shfl_down(a4, off);
            a5 += __shfl_down(a5, off);
        }
    }
    if (lane != 0) return;

    float di = dinv[v];
    float t[F];
    t[0] = di * a0; t[1] = di * a1; t[2] = di * a2;
    if constexpr (F == 6) { t[3] = di * a3; t[4] = di * a4; t[5] = di * a5; }

    float y[6];
#pragma unroll
    for (int j = 0; j < 6; ++j) {
        float acc = b[j];
#pragma unroll
        for (int k = 0; k < F; ++k) acc += t[k] * W[k * 6 + j];
        y[j] = acc;
    }

    if constexpr (MODE == 0) {
        float* o = xsout + (size_t)v * 8;
        *(float4*)o = make_float4(di * y[0], di * y[1], di * y[2], di * y[3]);
        *(float2*)(o + 4) = make_float2(di * y[4], di * y[5]);
    } else {
        float mu = 0.f;
#pragma unroll
        for (int j = 0; j < 6; ++j) mu += y[j];
        mu *= (1.f / 6.f);
        float var = 0.f;
#pragma unroll
        for (int j = 0; j < 6; ++j) { float dl = y[j] - mu; var += dl * dl; }
        var *= (1.f / 6.f);
        float rs = rsqrtf(var + EPSLN);
        float sq = sqd[v];
        const float* xr = xs + (size_t)v * 8;   // residual = xs * sqrt(deg+1)
        float r[6];
#pragma unroll
        for (int j = 0; j < 6; ++j) {
            float z = (y[j] - mu) * rs * gamma[j] + beta[j] + xr[j] * sq;
            r[j] = z > 0.f ? z : 0.f;
        }
        if constexpr (MODE == 1) {
            float* o = xsout + (size_t)v * 8;
            *(float4*)o = make_float4(di * r[0], di * r[1], di * r[2], di * r[3]);
            *(float2*)(o + 4) = make_float2(di * r[4], di * r[5]);
        } else {
#pragma unroll
            for (int j = 0; j < 3; ++j) {
                float acc = bfc[j];
#pragma unroll
                for (int k = 0; k < 6; ++k) acc += r[k] * Wfc[k * 3 + j];
                outfc[(size_t)v * 3 + j] = acc;
            }
        }
    }
}

// ---------------------------------------------------------------------------
extern "C" void kernel_launch(void* const* d_in, const int* in_sizes, int n_in,
                              void* d_out, int out_size, void* d_ws, size_t ws_size,
                              hipStream_t stream) {
    const float* node  = (const float*)d_in[0];
    const int*   edges = (const int*)d_in[1];
    const float* W1    = (const float*)d_in[2];
    const float* b1    = (const float*)d_in[3];
    const float* Wl    = (const float*)d_in[4];
    const float* bl    = (const float*)d_in[5];
    const float* gamma = (const float*)d_in[6];
    const float* beta  = (const float*)d_in[7];
    const float* Wfc   = (const float*)d_in[8];
    const float* bfc   = (const float*)d_in[9];
    float* out = (float*)d_out;

    const int N     = in_sizes[0] / 3;
    const int E     = in_sizes[1] / 2;
    const int STEPS = in_sizes[4] / 36;
    const int* src = edges;
    const int* dst = edges + E;
    const int B = (N + NPB - 1) / NPB;   // 1563 for N=200000 (<= MAXB)

    char* ws = (char*)d_ws;
    size_t off = 0;
    auto alloc = [&](size_t bytes) -> void* {
        void* p = ws + off;
        off += (bytes + 255) & ~(size_t)255;
        return p;
    };
    int*   bcount = (int*)alloc((size_t)B * sizeof(int));
    int*   boff   = (int*)alloc((size_t)(B + 1) * sizeof(int));
    int*   bcur   = (int*)alloc((size_t)B * sizeof(int));
    int*   ptr    = (int*)alloc((size_t)(N + 1) * sizeof(int));
    float* dinv   = (float*)alloc((size_t)N * sizeof(float));
    float* sqd    = (float*)alloc((size_t)N * sizeof(float));
    int*   packed = (int*)alloc((size_t)E * sizeof(int));   // becomes csr in place
    float* xs3    = (float*)alloc((size_t)N * 4 * sizeof(float));
    float* xsa    = (float*)alloc((size_t)N * 8 * sizeof(float));
    float* xsb    = (float*)alloc((size_t)N * 8 * sizeof(float));
    (void)ws_size;

    const int T = 256;
    const int gS = (E + TILE - 1) / TILE;
    const int gC = (N + 3) / 4;

    hipMemsetAsync(bcount, 0, (size_t)B * sizeof(int), stream);
    k_hist<<<gS, T, 0, stream>>>(dst, bcount, E, B);
    k_bscan<<<1, 1024, 0, stream>>>(bcount, boff, bcur, ptr, B, N, E);
    k_scatter<<<gS, T, 0, stream>>>(src, dst, bcur, packed, E, B);
    k_fine<<<B, T, 0, stream>>>(boff, packed, ptr, dinv, sqd, node, xs3, N);

    // Conv 1 (F=3): xsa = dinv * ((A_hat @ node) @ W1 + b1)
    k_conv<0><<<gC, T, 0, stream>>>(ptr, packed, dinv, sqd, xs3, W1, b1,
                                    nullptr, nullptr, nullptr, nullptr,
                                    xsa, nullptr, N);

    float* xscur = xsa;
    float* xsnxt = xsb;
    for (int i = 0; i < STEPS; ++i) {
        const float* W  = Wl + (size_t)i * 36;
        const float* bb = bl + (size_t)i * 6;
        const float* g  = gamma + (size_t)i * 6;
        const float* be = beta + (size_t)i * 6;
        if (i == STEPS - 1) {
            k_conv<2><<<gC, T, 0, stream>>>(ptr, packed, dinv, sqd, xscur, W, bb,
                                            g, be, Wfc, bfc, nullptr, out, N);
        } else {
            k_conv<1><<<gC, T, 0, stream>>>(ptr, packed, dinv, sqd, xscur, W, bb,
                                            g, be, nullptr, nullptr, xsnxt, nullptr, N);
        }
        float* tmp = xscur; xscur = xsnxt; xsnxt = tmp;
    }
}

// Round 4
// 992.375 us; speedup vs baseline: 17.8458x; 1.2694x over previous
//
#include <hip/hip_runtime.h>
#include <hip/hip_fp16.h>
#include <cstdint>

#define EPSLN 1e-5f
#define NPB 1024         // nodes per bucket (power of 2)
#define NPB_SHIFT 10
#define MAXB 256         // max buckets (N <= 262144)
#define TILE 32768       // edges per sort tile
#define SRC_BITS 18      // src id fits 18 bits (N <= 262144)
#define SRC_MASK 0x3FFFF

// ---------------------------------------------------------------------------
// Pass 1: per-bucket histogram of dst
// ---------------------------------------------------------------------------
__global__ __launch_bounds__(256) void k_hist(const int* __restrict__ dst,
                                              int* __restrict__ bcount, int E, int B) {
    __shared__ int hist[MAXB];
    if (threadIdx.x < B) hist[threadIdx.x] = 0;
    __syncthreads();
    int beg = blockIdx.x * TILE;
    int end = min(beg + TILE, E);
    for (int i = beg + threadIdx.x; i < end; i += 256)
        atomicAdd(&hist[__builtin_nontemporal_load(dst + i) >> NPB_SHIFT], 1);
    __syncthreads();
    if (threadIdx.x < B && hist[threadIdx.x])
        atomicAdd(&bcount[threadIdx.x], hist[threadIdx.x]);
}

// ---------------------------------------------------------------------------
// Pass 2: scan bucket counts -> boff / bcur; seed ptr[N]=E
// ---------------------------------------------------------------------------
__global__ __launch_bounds__(256) void k_bscan(const int* __restrict__ bcount,
                                               int* __restrict__ boff,
                                               int* __restrict__ bcur,
                                               int* __restrict__ ptr,
                                               int B, int N, int E) {
    __shared__ int sm[256];
    int v = (threadIdx.x < B) ? bcount[threadIdx.x] : 0;
    sm[threadIdx.x] = v;
    __syncthreads();
    for (int off = 1; off < 256; off <<= 1) {
        int t = (threadIdx.x >= off) ? sm[threadIdx.x - off] : 0;
        __syncthreads();
        sm[threadIdx.x] += t;
        __syncthreads();
    }
    if (threadIdx.x < B) {
        int e = sm[threadIdx.x] - v;
        boff[threadIdx.x] = e;
        bcur[threadIdx.x] = e;
    }
    if (threadIdx.x == 0) { boff[B] = E; ptr[N] = E; }
}

// ---------------------------------------------------------------------------
// Pass 3: tiled bucket scatter. Packed word = (dst_local << 18) | src.
// 196 buckets x ~167 edges per tile -> ~668B contiguous chunks per bucket.
// ---------------------------------------------------------------------------
__global__ __launch_bounds__(256) void k_scatter(const int* __restrict__ src,
                                                 const int* __restrict__ dst,
                                                 int* __restrict__ bcur,
                                                 unsigned* __restrict__ packed,
                                                 int E, int B) {
    __shared__ int hist[MAXB];
    __shared__ int base[MAXB];
    if (threadIdx.x < B) hist[threadIdx.x] = 0;
    __syncthreads();
    int beg = blockIdx.x * TILE;
    int end = min(beg + TILE, E);
    for (int i = beg + threadIdx.x; i < end; i += 256)
        atomicAdd(&hist[dst[i] >> NPB_SHIFT], 1);
    __syncthreads();
    if (threadIdx.x < B) {
        int c = hist[threadIdx.x];
        base[threadIdx.x] = c ? atomicAdd(&bcur[threadIdx.x], c) : 0;
        hist[threadIdx.x] = 0;
    }
    __syncthreads();
    for (int i = beg + threadIdx.x; i < end; i += 256) {
        int d = dst[i];
        int s = src[i];
        int bkt = d >> NPB_SHIFT;
        int pos = base[bkt] + atomicAdd(&hist[bkt], 1);
        packed[pos] = ((unsigned)(d & (NPB - 1)) << SRC_BITS) | (unsigned)s;
    }
}

// ---------------------------------------------------------------------------
// Pass 4: per-bucket fine sort (two-pass over packed, no staging; writes stay
// in the block's private 256KB csr region) + fused degree/dinv/ptr/xs3.
// ---------------------------------------------------------------------------
__global__ __launch_bounds__(1024) void k_fine(const int* __restrict__ boff,
                                               const unsigned* __restrict__ packed,
                                               int* __restrict__ csr,
                                               int* __restrict__ ptr,
                                               float* __restrict__ dinv,
                                               float* __restrict__ sqd,
                                               const float* __restrict__ node,
                                               float* __restrict__ xs3,   // [N,4]
                                               int N) {
    __shared__ int hist[NPB];
    __shared__ int cur[NPB];
    int b = blockIdx.x;
    int beg = boff[b], end = boff[b + 1];
    int tid = threadIdx.x;
    hist[tid] = 0;
    __syncthreads();
    for (int i = beg + tid; i < end; i += 1024)
        atomicAdd(&hist[packed[i] >> SRC_BITS], 1);
    __syncthreads();
    int hv = hist[tid];
    cur[tid] = hv;
    __syncthreads();
    for (int off = 1; off < NPB; off <<= 1) {
        int t = (tid >= off) ? cur[tid - off] : 0;
        __syncthreads();
        cur[tid] += t;
        __syncthreads();
    }
    int ex = cur[tid] - hv;  // exclusive
    int v = b * NPB + tid;
    if (v < N) {
        ptr[v] = beg + ex;
        float c = (float)(hv + 1);      // +1: self-loop
        float di = rsqrtf(c);
        dinv[v] = di;
        sqd[v] = sqrtf(c);              // = 1/di, residual reconstruction
        xs3[(size_t)v * 4 + 0] = di * node[(size_t)v * 3 + 0];
        xs3[(size_t)v * 4 + 1] = di * node[(size_t)v * 3 + 1];
        xs3[(size_t)v * 4 + 2] = di * node[(size_t)v * 3 + 2];
        xs3[(size_t)v * 4 + 3] = 0.f;
    }
    cur[tid] = ex;  // placement cursor
    __syncthreads();
    for (int i = beg + tid; i < end; i += 1024) {
        unsigned w = packed[i];
        int dl = (int)(w >> SRC_BITS);
        int pos = atomicAdd(&cur[dl], 1);
        csr[beg + pos] = (int)(w & SRC_MASK);
    }
}

// ---------------------------------------------------------------------------
// Fused conv. Gathers from fp16 xsh (16B/edge); self-loop + residual from
// fp32 xs. MODE 0: first conv (F=3, fp32 float4 gathers from xs3).
// MODE 1: mid layer -> LN+res+relu. MODE 2: final -> @Wfc+bfc -> out.
// ---------------------------------------------------------------------------
template <int MODE>
__global__ __launch_bounds__(256) void k_conv(const int* __restrict__ ptr,
                                              const int* __restrict__ csr,
                                              const float* __restrict__ dinv,
                                              const float* __restrict__ sqd,
                                              const float* __restrict__ xs,   // fp32: MODE0 [N,4], else [N,8]
                                              const __half* __restrict__ xsh, // fp16 [N,8] (MODE1/2)
                                              const float* __restrict__ W,
                                              const float* __restrict__ b,
                                              const float* __restrict__ gamma,
                                              const float* __restrict__ beta,
                                              const float* __restrict__ Wfc,
                                              const float* __restrict__ bfc,
                                              float* __restrict__ xsout,      // fp32 [N,8]
                                              __half* __restrict__ xhout,     // fp16 [N,8]
                                              float* __restrict__ outfc,      // [N,3]
                                              int N) {
    constexpr int F = (MODE == 0) ? 3 : 6;
    int wave = threadIdx.x >> 6;
    int lane = threadIdx.x & 63;
    int v = blockIdx.x * 4 + wave;
    if (v >= N) return;
    int beg = ptr[v], end = ptr[v + 1];

    float a0 = 0.f, a1 = 0.f, a2 = 0.f, a3 = 0.f, a4 = 0.f, a5 = 0.f;
    if constexpr (F == 3) {
        const float4* x4 = (const float4*)xs;
        for (int i = beg + lane; i < end; i += 64) {
            float4 p = x4[csr[i]];
            a0 += p.x; a1 += p.y; a2 += p.z;
        }
        if (lane == 0) { float4 p = x4[v]; a0 += p.x; a1 += p.y; a2 += p.z; }
    } else {
        const float4* xh4 = (const float4*)xsh;  // 8 halves = 16B
        for (int i = beg + lane; i < end; i += 64) {
            float4 raw = xh4[csr[i]];
            const __half2* h2 = (const __half2*)&raw;
            float2 p0 = __half22float2(h2[0]);
            float2 p1 = __half22float2(h2[1]);
            float2 p2 = __half22float2(h2[2]);
            a0 += p0.x; a1 += p0.y; a2 += p1.x; a3 += p1.y; a4 += p2.x; a5 += p2.y;
        }
        if (lane == 0) {  // self-loop, fp32
            const float* r = xs + (size_t)v * 8;
            float4 p = *(const float4*)r;
            float2 q = *(const float2*)(r + 4);
            a0 += p.x; a1 += p.y; a2 += p.z; a3 += p.w; a4 += q.x; a5 += q.y;
        }
    }
#pragma unroll
    for (int off = 32; off >= 1; off >>= 1) {
        a0 += __shfl_down(a0, off);
        a1 += __shfl_down(a1, off);
        a2 += __shfl_down(a2, off);
        if constexpr (F == 6) {
            a3 += __shfl_down(a3, off);
            a4 += __shfl_down(a4, off);
            a5 += __shfl_down(a5, off);
        }
    }
    if (lane != 0) return;

    float di = dinv[v];
    float t[F];
    t[0] = di * a0; t[1] = di * a1; t[2] = di * a2;
    if constexpr (F == 6) { t[3] = di * a3; t[4] = di * a4; t[5] = di * a5; }

    float y[6];
#pragma unroll
    for (int j = 0; j < 6; ++j) {
        float acc = b[j];
#pragma unroll
        for (int k = 0; k < F; ++k) acc += t[k] * W[k * 6 + j];
        y[j] = acc;
    }

    if constexpr (MODE == 0) {
        float* o = xsout + (size_t)v * 8;
        *(float4*)o = make_float4(di * y[0], di * y[1], di * y[2], di * y[3]);
        *(float2*)(o + 4) = make_float2(di * y[4], di * y[5]);
        __half2* oh = (__half2*)(xhout + (size_t)v * 8);
        oh[0] = __floats2half2_rn(di * y[0], di * y[1]);
        oh[1] = __floats2half2_rn(di * y[2], di * y[3]);
        oh[2] = __floats2half2_rn(di * y[4], di * y[5]);
        oh[3] = __floats2half2_rn(0.f, 0.f);
    } else {
        float mu = 0.f;
#pragma unroll
        for (int j = 0; j < 6; ++j) mu += y[j];
        mu *= (1.f / 6.f);
        float var = 0.f;
#pragma unroll
        for (int j = 0; j < 6; ++j) { float dl = y[j] - mu; var += dl * dl; }
        var *= (1.f / 6.f);
        float rs = rsqrtf(var + EPSLN);
        float sq = sqd[v];
        const float* xr = xs + (size_t)v * 8;   // residual = xs * sqrt(deg+1)
        float r[6];
#pragma unroll
        for (int j = 0; j < 6; ++j) {
            float z = (y[j] - mu) * rs * gamma[j] + beta[j] + xr[j] * sq;
            r[j] = z > 0.f ? z : 0.f;
        }
        if constexpr (MODE == 1) {
            float* o = xsout + (size_t)v * 8;
            *(float4*)o = make_float4(di * r[0], di * r[1], di * r[2], di * r[3]);
            *(float2*)(o + 4) = make_float2(di * r[4], di * r[5]);
            __half2* oh = (__half2*)(xhout + (size_t)v * 8);
            oh[0] = __floats2half2_rn(di * r[0], di * r[1]);
            oh[1] = __floats2half2_rn(di * r[2], di * r[3]);
            oh[2] = __floats2half2_rn(di * r[4], di * r[5]);
            oh[3] = __floats2half2_rn(0.f, 0.f);
        } else {
#pragma unroll
            for (int j = 0; j < 3; ++j) {
                float acc = bfc[j];
#pragma unroll
                for (int k = 0; k < 6; ++k) acc += r[k] * Wfc[k * 3 + j];
                outfc[(size_t)v * 3 + j] = acc;
            }
        }
    }
}

// ---------------------------------------------------------------------------
extern "C" void kernel_launch(void* const* d_in, const int* in_sizes, int n_in,
                              void* d_out, int out_size, void* d_ws, size_t ws_size,
                              hipStream_t stream) {
    const float* node  = (const float*)d_in[0];
    const int*   edges = (const int*)d_in[1];
    const float* W1    = (const float*)d_in[2];
    const float* b1    = (const float*)d_in[3];
    const float* Wl    = (const float*)d_in[4];
    const float* bl    = (const float*)d_in[5];
    const float* gamma = (const float*)d_in[6];
    const float* beta  = (const float*)d_in[7];
    const float* Wfc   = (const float*)d_in[8];
    const float* bfc   = (const float*)d_in[9];
    float* out = (float*)d_out;

    const int N     = in_sizes[0] / 3;
    const int E     = in_sizes[1] / 2;
    const int STEPS = in_sizes[4] / 36;
    const int* src = edges;
    const int* dst = edges + E;
    const int B = (N + NPB - 1) / NPB;   // 196 for N=200000

    char* ws = (char*)d_ws;
    size_t off = 0;
    auto alloc = [&](size_t bytes) -> void* {
        void* p = ws + off;
        off += (bytes + 255) & ~(size_t)255;
        return p;
    };
    int*      bcount = (int*)alloc((size_t)B * sizeof(int));
    int*      boff   = (int*)alloc((size_t)(B + 1) * sizeof(int));
    int*      bcur   = (int*)alloc((size_t)B * sizeof(int));
    int*      ptr    = (int*)alloc((size_t)(N + 1) * sizeof(int));
    float*    dinv   = (float*)alloc((size_t)N * sizeof(float));
    float*    sqd    = (float*)alloc((size_t)N * sizeof(float));
    unsigned* packed = (unsigned*)alloc((size_t)E * sizeof(unsigned));
    int*      csr    = (int*)alloc((size_t)E * sizeof(int));
    float*    xs3    = (float*)alloc((size_t)N * 4 * sizeof(float));
    float*    xsa    = (float*)alloc((size_t)N * 8 * sizeof(float));
    float*    xsb    = (float*)alloc((size_t)N * 8 * sizeof(float));
    __half*   xha    = (__half*)alloc((size_t)N * 8 * sizeof(__half));
    __half*   xhb    = (__half*)alloc((size_t)N * 8 * sizeof(__half));
    (void)ws_size;

    const int T = 256;
    const int gS = (E + TILE - 1) / TILE;
    const int gC = (N + 3) / 4;

    hipMemsetAsync(bcount, 0, (size_t)B * sizeof(int), stream);
    k_hist<<<gS, T, 0, stream>>>(dst, bcount, E, B);
    k_bscan<<<1, T, 0, stream>>>(bcount, boff, bcur, ptr, B, N, E);
    k_scatter<<<gS, T, 0, stream>>>(src, dst, bcur, packed, E, B);
    k_fine<<<B, 1024, 0, stream>>>(boff, packed, csr, ptr, dinv, sqd, node, xs3, N);

    // Conv 1 (F=3): xsa/xha = dinv * ((A_hat @ node) @ W1 + b1)
    k_conv<0><<<gC, T, 0, stream>>>(ptr, csr, dinv, sqd, xs3, nullptr, W1, b1,
                                    nullptr, nullptr, nullptr, nullptr,
                                    xsa, xha, nullptr, N);

    float* xscur = xsa;   __half* xhcur = xha;
    float* xsnxt = xsb;   __half* xhnxt = xhb;
    for (int i = 0; i < STEPS; ++i) {
        const float* W  = Wl + (size_t)i * 36;
        const float* bb = bl + (size_t)i * 6;
        const float* g  = gamma + (size_t)i * 6;
        const float* be = beta + (size_t)i * 6;
        if (i == STEPS - 1) {
            k_conv<2><<<gC, T, 0, stream>>>(ptr, csr, dinv, sqd, xscur, xhcur, W, bb,
                                            g, be, Wfc, bfc, nullptr, nullptr, out, N);
        } else {
            k_conv<1><<<gC, T, 0, stream>>>(ptr, csr, dinv, sqd, xscur, xhcur, W, bb,
                                            g, be, nullptr, nullptr, xsnxt, xhnxt, nullptr, N);
        }
        float* t1 = xscur; xscur = xsnxt; xsnxt = t1;
        __half* t2 = xhcur; xhcur = xhnxt; xhnxt = t2;
    }
}